// Round 6
// baseline (161.209 us; speedup 1.0000x reference)
//
#include <hip/hip_runtime.h>

#define IS 256
#define FCOUNT 4096
#define NEARP 0.1f
#define FARP 100.0f
#define TINYF 1e-12f
#define BBOX_MARGIN 2e-3f   // covers fp-inside dilation for det >= DET_SLIVER
#define DET_SLIVER 3e-4f    // flatter faces are tested in EVERY tile

// Value barrier: pins a value in a VGPR; no transform across it.
__device__ __forceinline__ float frn(float r) { asm("" : "+v"(r)); return r; }
__device__ __forceinline__ float mulrn(float a, float b) { return frn(a * b); }
__device__ __forceinline__ float addrn(float a, float b) { return frn(a + b); }
__device__ __forceinline__ float subrn(float a, float b) { return frn(a - b); }
__device__ __forceinline__ float divrn(float a, float b) { return frn(a / b); }
__device__ __forceinline__ float fmarn(float a, float b, float c) {
    return frn(__builtin_fmaf(a, b, c));
}

// Contracted-evaluation model of the reference (XLA/clang fma contraction):
//   C  = fma(xa, yb, -(xb*ya))           [LHS mul folded, RHS mul rounded]
//   w  = fma(yp, A, xp*B) + C            [inner add folds LHS mul; outer plain]
// All other ops (det sum, div, clip, renorm, inv_zp, tif, trilinear) have no
// mul+add pattern -> per-op IEEE in source order, as before.
__global__ __launch_bounds__(256) void raster_kernel(
    const float* __restrict__ faces,     // (B, F, 3, 3)
    const float* __restrict__ textures,  // (B, F, 4, 4, 4, 3)
    float* __restrict__ out,             // (B, 256, 256, 5)
    int B, int F)
{
    const int tid  = threadIdx.x;
    const int lane = tid & 63;
    const int wv   = tid >> 6;
    const int b    = blockIdx.x >> 8;     // 256 tiles per image
    const int tile = blockIdx.x & 255;
    const int tx0  = (tile & 15) * 16;
    const int ty0  = (tile >> 4) * 16;
    const int px   = tx0 + (tid & 15);
    const int py   = ty0 + (tid >> 4);
    const float xp = (float)(2 * px + 1 - IS) * (1.0f / IS);  // exact (/2^8)
    const float yp = (float)(2 * py + 1 - IS) * (1.0f / IS);  // exact
    const float txlo = (float)(2 * tx0 + 1 - IS)        * (1.0f / IS) - BBOX_MARGIN;
    const float txhi = (float)(2 * (tx0 + 15) + 1 - IS) * (1.0f / IS) + BBOX_MARGIN;
    const float tylo = (float)(2 * ty0 + 1 - IS)        * (1.0f / IS) - BBOX_MARGIN;
    const float tyhi = (float)(2 * (ty0 + 15) + 1 - IS) * (1.0f / IS) + BBOX_MARGIN;

    __shared__ float4 s_a[256];   // A0,B0,C0,A1
    __shared__ float4 s_b[256];   // B1,C1,A2,B2
    __shared__ float4 s_c[256];   // C2,z0,z1,z2
    __shared__ int    s_idx[256];
    __shared__ int    s_wcnt[4];

    float bestz = FARP;
    int   besti = -1;

    const float* fbase = faces + (size_t)b * F * 9;

    for (int base = 0; base < F; base += 256) {
        const int f = base + tid;
        const float* fp = fbase + (size_t)f * 9;
        const float x0 = fp[0], y0 = fp[1], z0 = fp[2];
        const float x1 = fp[3], y1 = fp[4], z1 = fp[5];
        const float x2 = fp[6], y2 = fp[7], z2 = fp[8];

        // Edge constants with contracted cross terms.
        const float A0 = subrn(x2, x1), B0 = subrn(y1, y2);
        const float C0 = fmarn(x1, y2, -mulrn(x2, y1));
        const float A1 = subrn(x0, x2), B1 = subrn(y2, y0);
        const float C1 = fmarn(x2, y0, -mulrn(x0, y2));
        const float A2 = subrn(x1, x0), B2 = subrn(y0, y1);
        const float C2 = fmarn(x0, y1, -mulrn(x1, y0));

        const float mnx = fminf(x0, fminf(x1, x2));
        const float mxx = fmaxf(x0, fmaxf(x1, x2));
        const float mny = fminf(y0, fminf(y1, y2));
        const float mxy = fmaxf(y0, fmaxf(y1, y2));
        const bool overlap = (mxx >= txlo) && (mnx <= txhi) &&
                             (mxy >= tylo) && (mny <= tyhi);
        const float detA = addrn(addrn(C0, C1), C2);   // pixel-independent part
        const bool keep = overlap || (fabsf(detA) < DET_SLIVER);
        const unsigned long long m = __ballot(keep);

        __syncthreads();  // previous chunk's inner loop fully done
        if (lane == 0) s_wcnt[wv] = __popcll(m);
        __syncthreads();  // wave counts visible

        int off = __popcll(m & ((1ull << lane) - 1ull));
        for (int w = 0; w < wv; ++w) off += s_wcnt[w];
        const int total = s_wcnt[0] + s_wcnt[1] + s_wcnt[2] + s_wcnt[3];

        if (keep) {
            s_a[off] = make_float4(A0, B0, C0, A1);
            s_b[off] = make_float4(B1, C1, A2, B2);
            s_c[off] = make_float4(C2, z0, z1, z2);
            s_idx[off] = f;
        }
        __syncthreads();  // compacted list visible

        for (int j = 0; j < total; ++j) {
            const float4 fa = s_a[j];
            const float4 fb = s_b[j];
            const float4 fc = s_c[j];
            // Contracted: w = fma(yp, A, xp*B) + C
            const float w0 = addrn(fmarn(yp, fa.x, mulrn(xp, fa.y)), fa.z);
            const float w1 = addrn(fmarn(yp, fa.w, mulrn(xp, fb.x)), fb.y);
            const float w2 = addrn(fmarn(yp, fb.z, mulrn(xp, fb.w)), fc.x);
            const float det = addrn(addrn(w0, w1), w2);
            // inside <=> all w same sign as det, |det| > TINY.
            bool ins;
            if (det > TINYF)       ins = (w0 > 0.f) && (w1 > 0.f) && (w2 > 0.f);
            else if (det < -TINYF) ins = (w0 < 0.f) && (w1 < 0.f) && (w2 < 0.f);
            else                   ins = false;
            if (ins) {
                float n0 = divrn(w0, det), n1 = divrn(w1, det), n2 = divrn(w2, det);
                n0 = frn(fminf(fmaxf(n0, 0.f), 1.f));
                n1 = frn(fminf(fmaxf(n1, 0.f), 1.f));
                n2 = frn(fminf(fmaxf(n2, 0.f), 1.f));
                float s = addrn(addrn(n0, n1), n2);
                s = (s > TINYF) ? s : 1.0f;
                n0 = divrn(n0, s); n1 = divrn(n1, s); n2 = divrn(n2, s);
                float iz = addrn(addrn(divrn(n0, fc.y), divrn(n1, fc.z)),
                                 divrn(n2, fc.w));
                iz = (fabsf(iz) > TINYF) ? iz : 1.0f;
                const float zp = divrn(1.0f, iz);
                if (zp > NEARP && zp < FARP && zp < bestz) {
                    bestz = zp;
                    besti = s_idx[j];
                }
            }
        }
    }

    // Phase C: shade the winning face (same contracted chain).
    float r = 0.f, g = 0.f, bch = 0.f, alpha = 0.f, depth = FARP;
    if (besti >= 0) {
        const float* fp = fbase + (size_t)besti * 9;
        const float x0 = fp[0], y0 = fp[1], z0 = fp[2];
        const float x1 = fp[3], y1 = fp[4], z1 = fp[5];
        const float x2 = fp[6], y2 = fp[7], z2 = fp[8];
        const float w0 = addrn(fmarn(yp, subrn(x2, x1), mulrn(xp, subrn(y1, y2))),
                               fmarn(x1, y2, -mulrn(x2, y1)));
        const float w1 = addrn(fmarn(yp, subrn(x0, x2), mulrn(xp, subrn(y2, y0))),
                               fmarn(x2, y0, -mulrn(x0, y2)));
        const float w2 = addrn(fmarn(yp, subrn(x1, x0), mulrn(xp, subrn(y0, y1))),
                               fmarn(x0, y1, -mulrn(x1, y0)));
        const float det = addrn(addrn(w0, w1), w2);
        const float sd = (fabsf(det) > TINYF) ? det : 1.0f;
        float n0 = divrn(w0, sd), n1 = divrn(w1, sd), n2 = divrn(w2, sd);
        n0 = frn(fminf(fmaxf(n0, 0.f), 1.f));
        n1 = frn(fminf(fmaxf(n1, 0.f), 1.f));
        n2 = frn(fminf(fmaxf(n2, 0.f), 1.f));
        float s = addrn(addrn(n0, n1), n2);
        s = (s > TINYF) ? s : 1.0f;
        n0 = divrn(n0, s); n1 = divrn(n1, s); n2 = divrn(n2, s);
        float iz = addrn(addrn(divrn(n0, z0), divrn(n1, z1)), divrn(n2, z2));
        iz = (fabsf(iz) > TINYF) ? iz : 1.0f;
        const float zp = divrn(1.0f, iz);
        depth = zp;

        // tif = clip(((n*3)*zp)/vz, 0, 3-EPS) — mul/mul/div, no contraction.
        const float t0 = fminf(fmaxf(divrn(mulrn(mulrn(n0, 3.0f), zp), z0), 0.f), 2.999f);
        const float t1 = fminf(fmaxf(divrn(mulrn(mulrn(n1, 3.0f), zp), z1), 0.f), 2.999f);
        const float t2 = fminf(fmaxf(divrn(mulrn(mulrn(n2, 3.0f), zp), z2), 0.f), 2.999f);
        const float l0 = floorf(t0), l1 = floorf(t1), l2 = floorf(t2);
        const float fr0 = subrn(t0, l0), fr1 = subrn(t1, l1), fr2 = subrn(t2, l2);
        const int i0 = (int)l0, i1 = (int)l1, i2 = (int)l2;

        const float* tx = textures + (size_t)(b * F + besti) * 64 * 3;
        for (int d0 = 0; d0 < 2; ++d0)
            for (int d1 = 0; d1 < 2; ++d1)
                for (int d2 = 0; d2 < 2; ++d2) {
                    const float wg = mulrn(mulrn(d0 ? fr0 : subrn(1.0f, fr0),
                                                 d1 ? fr1 : subrn(1.0f, fr1)),
                                           d2 ? fr2 : subrn(1.0f, fr2));
                    const float* tp = tx + ((i0 + d0) * 16 + (i1 + d1) * 4 + (i2 + d2)) * 3;
                    r   = addrn(r,   mulrn(wg, tp[0]));
                    g   = addrn(g,   mulrn(wg, tp[1]));
                    bch = addrn(bch, mulrn(wg, tp[2]));
                }
        alpha = 1.0f;
    }

    float* op = out + (((size_t)b * IS + py) * IS + px) * 5;
    op[0] = r;
    op[1] = g;
    op[2] = bch;
    op[3] = alpha;
    op[4] = depth;
}

extern "C" void kernel_launch(void* const* d_in, const int* in_sizes, int n_in,
                              void* d_out, int out_size, void* d_ws, size_t ws_size,
                              hipStream_t stream) {
    const float* faces    = (const float*)d_in[0];
    const float* textures = (const float*)d_in[1];
    float* out = (float*)d_out;
    const int F = FCOUNT;
    const int B = in_sizes[0] / (F * 9);
    dim3 grid(B * 256);
    dim3 block(256);
    raster_kernel<<<grid, block, 0, stream>>>(faces, textures, out, B, F);
}

// Round 7
// 112.732 us; speedup vs baseline: 1.4300x; 1.4300x over previous
//
#include <hip/hip_runtime.h>

#define IS 256
#define FCOUNT 4096
#define NEARP 0.1f
#define FARP 100.0f
#define TINYF 1e-12f
#define BBOX_MARGIN 2e-3f   // covers fp-inside dilation for det >= DET_SLIVER
#define DET_SLIVER 4e-5f    // escape <= 2e-7*0.2/4e-5 = 1e-3 < margin (2x safe)

// Value barrier: pins a value in a VGPR; no transform across it.
__device__ __forceinline__ float frn(float r) { asm("" : "+v"(r)); return r; }
__device__ __forceinline__ float mulrn(float a, float b) { return frn(a * b); }
__device__ __forceinline__ float addrn(float a, float b) { return frn(a + b); }
__device__ __forceinline__ float subrn(float a, float b) { return frn(a - b); }
__device__ __forceinline__ float divrn(float a, float b) { return frn(a / b); }
__device__ __forceinline__ float fmarn(float a, float b, float c) {
    return frn(__builtin_fmaf(a, b, c));
}

// Contracted-evaluation model of the reference (verified R6):
//   C  = fma(xa, yb, -(xb*ya));  w = fma(yp, A, xp*B) + C
// All other ops per-op IEEE f32 in source order.
//
// Structure (R7): block = 16x16 pixel tile, each of the 4 waves owns an 8x8
// quadrant. Faces stream in 64-wide chunks; each wave ballot-compacts its
// quadrant's survivors into wave-private LDS and scans them immediately.
// Wave-synchronous -> ZERO __syncthreads. Strict < keeps smallest face index
// (matches the reference's chunked argmin + strict-better scan).
__global__ __launch_bounds__(256) void raster_kernel(
    const float* __restrict__ faces,     // (B, F, 3, 3)
    const float* __restrict__ textures,  // (B, F, 4, 4, 4, 3)
    float* __restrict__ out,             // (B, 256, 256, 5)
    int B, int F)
{
    const int tid  = threadIdx.x;
    const int lane = tid & 63;
    const int w    = tid >> 6;            // wave id = quadrant id
    const int b    = blockIdx.x >> 8;     // 256 tiles per image
    const int tile = blockIdx.x & 255;
    const int qx0  = (tile & 15) * 16 + (w & 1) * 8;   // quadrant origin (px)
    const int qy0  = (tile >> 4) * 16 + (w >> 1) * 8;
    const int px   = qx0 + (lane & 7);
    const int py   = qy0 + (lane >> 3);
    const float xp = (float)(2 * px + 1 - IS) * (1.0f / IS);  // exact (/2^8)
    const float yp = (float)(2 * py + 1 - IS) * (1.0f / IS);  // exact
    const float qxlo = (float)(2 * qx0 + 1 - IS)       * (1.0f / IS) - BBOX_MARGIN;
    const float qxhi = (float)(2 * (qx0 + 7) + 1 - IS) * (1.0f / IS) + BBOX_MARGIN;
    const float qylo = (float)(2 * qy0 + 1 - IS)       * (1.0f / IS) - BBOX_MARGIN;
    const float qyhi = (float)(2 * (qy0 + 7) + 1 - IS) * (1.0f / IS) + BBOX_MARGIN;

    __shared__ float4 s_a[4][64];   // A0,B0,C0,A1   (wave-private rows)
    __shared__ float4 s_b[4][64];   // B1,C1,A2,B2
    __shared__ float4 s_c[4][64];   // C2,z0,z1,z2
    __shared__ int    s_idx[4][64];

    float bestz = FARP;
    int   besti = -1;

    const float* fbase = faces + (size_t)b * F * 9;

    for (int base = 0; base < F; base += 64) {
        const int f = base + lane;
        const float* fp = fbase + (size_t)f * 9;
        const float x0 = fp[0], y0 = fp[1], z0 = fp[2];
        const float x1 = fp[3], y1 = fp[4], z1 = fp[5];
        const float x2 = fp[6], y2 = fp[7], z2 = fp[8];

        // Edge constants with contracted cross terms (numpy/XLA-identical).
        const float A0 = subrn(x2, x1), B0 = subrn(y1, y2);
        const float C0 = fmarn(x1, y2, -mulrn(x2, y1));
        const float A1 = subrn(x0, x2), B1 = subrn(y2, y0);
        const float C1 = fmarn(x2, y0, -mulrn(x0, y2));
        const float A2 = subrn(x1, x0), B2 = subrn(y0, y1);
        const float C2 = fmarn(x0, y1, -mulrn(x1, y0));

        const float mnx = fminf(x0, fminf(x1, x2));
        const float mxx = fmaxf(x0, fmaxf(x1, x2));
        const float mny = fminf(y0, fminf(y1, y2));
        const float mxy = fmaxf(y0, fmaxf(y1, y2));
        const bool overlap = (mxx >= qxlo) && (mnx <= qxhi) &&
                             (mxy >= qylo) && (mny <= qyhi);
        const float detA = addrn(addrn(C0, C1), C2);   // pixel-independent part
        const bool keep = overlap || (fabsf(detA) < DET_SLIVER);
        const unsigned long long m = __ballot(keep);
        if (m == 0ull) continue;   // whole chunk culled for this quadrant

        const int n = __popcll(m);
        const int off = __popcll(m & ((1ull << lane) - 1ull));
        if (keep) {
            s_a[w][off] = make_float4(A0, B0, C0, A1);
            s_b[w][off] = make_float4(B1, C1, A2, B2);
            s_c[w][off] = make_float4(C2, z0, z1, z2);
            s_idx[w][off] = f;
        }
        __builtin_amdgcn_wave_barrier();  // order LDS write -> read (free)

        for (int j = 0; j < n; ++j) {
            const float4 fa = s_a[w][j];
            const float4 fb = s_b[w][j];
            const float4 fc = s_c[w][j];
            // Contracted: w = fma(yp, A, xp*B) + C
            const float w0 = addrn(fmarn(yp, fa.x, mulrn(xp, fa.y)), fa.z);
            const float w1 = addrn(fmarn(yp, fa.w, mulrn(xp, fb.x)), fb.y);
            const float w2 = addrn(fmarn(yp, fb.z, mulrn(xp, fb.w)), fc.x);
            const float det = addrn(addrn(w0, w1), w2);
            // inside <=> all w same sign as det, |det| > TINY.
            bool ins;
            if (det > TINYF)       ins = (w0 > 0.f) && (w1 > 0.f) && (w2 > 0.f);
            else if (det < -TINYF) ins = (w0 < 0.f) && (w1 < 0.f) && (w2 < 0.f);
            else                   ins = false;
            if (ins) {
                float n0 = divrn(w0, det), n1 = divrn(w1, det), n2 = divrn(w2, det);
                n0 = frn(fminf(fmaxf(n0, 0.f), 1.f));
                n1 = frn(fminf(fmaxf(n1, 0.f), 1.f));
                n2 = frn(fminf(fmaxf(n2, 0.f), 1.f));
                float s = addrn(addrn(n0, n1), n2);
                s = (s > TINYF) ? s : 1.0f;
                n0 = divrn(n0, s); n1 = divrn(n1, s); n2 = divrn(n2, s);
                float iz = addrn(addrn(divrn(n0, fc.y), divrn(n1, fc.z)),
                                 divrn(n2, fc.w));
                iz = (fabsf(iz) > TINYF) ? iz : 1.0f;
                const float zp = divrn(1.0f, iz);
                if (zp > NEARP && zp < FARP && zp < bestz) {
                    bestz = zp;
                    besti = s_idx[w][j];
                }
            }
        }
    }

    // Phase C: shade the winning face (same contracted chain).
    float r = 0.f, g = 0.f, bch = 0.f, alpha = 0.f, depth = FARP;
    if (besti >= 0) {
        const float* fp = fbase + (size_t)besti * 9;
        const float x0 = fp[0], y0 = fp[1], z0 = fp[2];
        const float x1 = fp[3], y1 = fp[4], z1 = fp[5];
        const float x2 = fp[6], y2 = fp[7], z2 = fp[8];
        const float w0 = addrn(fmarn(yp, subrn(x2, x1), mulrn(xp, subrn(y1, y2))),
                               fmarn(x1, y2, -mulrn(x2, y1)));
        const float w1 = addrn(fmarn(yp, subrn(x0, x2), mulrn(xp, subrn(y2, y0))),
                               fmarn(x2, y0, -mulrn(x0, y2)));
        const float w2 = addrn(fmarn(yp, subrn(x1, x0), mulrn(xp, subrn(y0, y1))),
                               fmarn(x0, y1, -mulrn(x1, y0)));
        const float det = addrn(addrn(w0, w1), w2);
        const float sd = (fabsf(det) > TINYF) ? det : 1.0f;
        float n0 = divrn(w0, sd), n1 = divrn(w1, sd), n2 = divrn(w2, sd);
        n0 = frn(fminf(fmaxf(n0, 0.f), 1.f));
        n1 = frn(fminf(fmaxf(n1, 0.f), 1.f));
        n2 = frn(fminf(fmaxf(n2, 0.f), 1.f));
        float s = addrn(addrn(n0, n1), n2);
        s = (s > TINYF) ? s : 1.0f;
        n0 = divrn(n0, s); n1 = divrn(n1, s); n2 = divrn(n2, s);
        float iz = addrn(addrn(divrn(n0, z0), divrn(n1, z1)), divrn(n2, z2));
        iz = (fabsf(iz) > TINYF) ? iz : 1.0f;
        const float zp = divrn(1.0f, iz);
        depth = zp;

        // tif = clip(((n*3)*zp)/vz, 0, 3-EPS) — mul/mul/div, no contraction.
        const float t0 = fminf(fmaxf(divrn(mulrn(mulrn(n0, 3.0f), zp), z0), 0.f), 2.999f);
        const float t1 = fminf(fmaxf(divrn(mulrn(mulrn(n1, 3.0f), zp), z1), 0.f), 2.999f);
        const float t2 = fminf(fmaxf(divrn(mulrn(mulrn(n2, 3.0f), zp), z2), 0.f), 2.999f);
        const float l0 = floorf(t0), l1 = floorf(t1), l2 = floorf(t2);
        const float fr0 = subrn(t0, l0), fr1 = subrn(t1, l1), fr2 = subrn(t2, l2);
        const int i0 = (int)l0, i1 = (int)l1, i2 = (int)l2;

        const float* tx = textures + (size_t)(b * F + besti) * 64 * 3;
        for (int d0 = 0; d0 < 2; ++d0)
            for (int d1 = 0; d1 < 2; ++d1)
                for (int d2 = 0; d2 < 2; ++d2) {
                    const float wg = mulrn(mulrn(d0 ? fr0 : subrn(1.0f, fr0),
                                                 d1 ? fr1 : subrn(1.0f, fr1)),
                                           d2 ? fr2 : subrn(1.0f, fr2));
                    const float* tp = tx + ((i0 + d0) * 16 + (i1 + d1) * 4 + (i2 + d2)) * 3;
                    r   = addrn(r,   mulrn(wg, tp[0]));
                    g   = addrn(g,   mulrn(wg, tp[1]));
                    bch = addrn(bch, mulrn(wg, tp[2]));
                }
        alpha = 1.0f;
    }

    float* op = out + (((size_t)b * IS + py) * IS + px) * 5;
    op[0] = r;
    op[1] = g;
    op[2] = bch;
    op[3] = alpha;
    op[4] = depth;
}

extern "C" void kernel_launch(void* const* d_in, const int* in_sizes, int n_in,
                              void* d_out, int out_size, void* d_ws, size_t ws_size,
                              hipStream_t stream) {
    const float* faces    = (const float*)d_in[0];
    const float* textures = (const float*)d_in[1];
    float* out = (float*)d_out;
    const int F = FCOUNT;
    const int B = in_sizes[0] / (F * 9);
    dim3 grid(B * 256);
    dim3 block(256);
    raster_kernel<<<grid, block, 0, stream>>>(faces, textures, out, B, F);
}